// Round 1
// baseline (787.949 us; speedup 1.0000x reference)
//
#include <hip/hip_runtime.h>
#include <hip/hip_bf16.h>
#include <cstdint>

#define B_    16
#define IC_   512
#define OC_   512
#define RES_  64
#define WDIM_ 512
#define HW_   4096

#define NT_ROWS 8
#define XROWS 10
#define XCOLS 66
#define XsEL (XROWS * XCOLS * 32)   // 21120 bf16

typedef __attribute__((ext_vector_type(8))) short short8;
typedef __attribute__((ext_vector_type(4))) float f32x4;

typedef __attribute__((address_space(3))) unsigned int lds_uint;
typedef const __attribute__((address_space(1))) unsigned int g_uint;

__device__ __forceinline__ unsigned int f2bf_bits(float f) {
    unsigned int x = __builtin_bit_cast(unsigned int, f);
    x += 0x7fffu + ((x >> 16) & 1u);   // RNE; inputs finite
    return x >> 16;
}

// ---------------- K0: styles = w @ (aw/sqrt(512))^T + ab ----------------
__global__ __launch_bounds__(256) void k_styles(const float* __restrict__ w,
        const float* __restrict__ aw, const float* __restrict__ ab,
        float* __restrict__ styles) {
    int bx = blockIdx.x;                     // 0..2047
    int b = bx >> 7;
    int wave = threadIdx.x >> 6, lane = threadIdx.x & 63;
    int ic = ((bx & 127) << 2) + wave;
    const float* wr = w + b * WDIM_;
    const float* awr = aw + ic * WDIM_;
    float s = 0.f;
    #pragma unroll
    for (int j = 0; j < 8; ++j) {
        int k = lane + (j << 6);
        s += wr[k] * awr[k];
    }
    #pragma unroll
    for (int off = 32; off > 0; off >>= 1) s += __shfl_down(s, off);
    if (lane == 0) styles[b * IC_ + ic] = s * 0.044194173824159216f + ab[ic];
}

// ---------------- K1: S2[oc,ic] = sum_k cw^2 ; wbf = bf16 pre-swizzled pack --
// wbf layout: [t(9)][chunk(16)][oc(512)][32 swizzled ic]   (4.72 MB)
__global__ __launch_bounds__(256) void k_wprep(const float* __restrict__ cw,
        float* __restrict__ S2, unsigned short* __restrict__ wbf) {
    int gid = blockIdx.x * 256 + threadIdx.x;   // 0..262143
    int oc = gid >> 9, ic = gid & 511;
    const float* p = cw + gid * 9;
    float v[9]; float ss = 0.f;
    #pragma unroll
    for (int t = 0; t < 9; ++t) { v[t] = p[t]; ss += v[t] * v[t]; }
    S2[gid] = ss;
    int chunk = ic >> 5;
    int gp = ((ic >> 3) & 3) ^ ((oc >> 2) & 3);
    int base = (chunk * 512 + oc) * 32 + gp * 8 + (ic & 7);
    #pragma unroll
    for (int t = 0; t < 9; ++t)
        wbf[t * (16 * 512 * 32) + base] = (unsigned short)f2bf_bits(v[t]);
}

// ---------------- K2: dcoefs[b,oc] = rsqrt(sum_ic styles^2 * S2 + 1e-8) -----
__global__ __launch_bounds__(256) void k_dcoef(const float* __restrict__ styles,
        const float* __restrict__ S2, float* __restrict__ dcoefs) {
    int bx = blockIdx.x;
    int b = bx >> 7;
    int wave = threadIdx.x >> 6, lane = threadIdx.x & 63;
    int oc = ((bx & 127) << 2) + wave;
    const float* st = styles + b * IC_;
    const float* s2 = S2 + oc * IC_;
    float s = 0.f;
    #pragma unroll
    for (int j = 0; j < 8; ++j) {
        int k = lane + (j << 6);
        float a = st[k];
        s += a * a * s2[k];
    }
    #pragma unroll
    for (int off = 32; off > 0; off >>= 1) s += __shfl_down(s, off);
    if (lane == 0) dcoefs[b * OC_ + oc] = rsqrtf(s + 1e-8f);
}

// ---------------- K3: main conv -------------------------------------------
// grid (8 ntile, 8 octile, 16 b), 256 thr (4 waves). BM=64 oc, BN=512 (8 rows).
__global__ __launch_bounds__(256, 2) void k_conv(
        const float* __restrict__ x, const float* __restrict__ styles,
        const float* __restrict__ dcoefs, const unsigned short* __restrict__ wbf,
        const float* __restrict__ bias, const float* __restrict__ noise,
        const float* __restrict__ nstr, float* __restrict__ out) {

    __shared__ __align__(16) unsigned short Xs[XsEL];        // 42.24 KB
    __shared__ __align__(16) unsigned short Wb[3][64 * 32];  // 12 KB
    __shared__ float st_s[IC_];                              // 2 KB

    const int tid = threadIdx.x;
    const int lane = tid & 63, wave = tid >> 6;
    const int lane15 = lane & 15, kg = lane >> 4;
    const int nt = blockIdx.x, oct = blockIdx.y, b = blockIdx.z;
    const int oc0 = oct * 64, r0 = nt * NT_ROWS;
    const float* xb = x + (size_t)b * IC_ * HW_;

    auto issueW = [&](int c2, int t2, int buf) {
        const unsigned short* src =
            wbf + (((t2 * 16 + c2) * 512 + oc0) * 32) + tid * 8;
        __builtin_amdgcn_global_load_lds((g_uint*)src,
            (lds_uint*)(&Wb[buf][tid * 8]), 16, 0, 0);
    };

    auto stage_x = [&](int c) {
        const int ic0 = c << 5;
        #pragma unroll
        for (int s5 = 0; s5 < 5; ++s5) {
            int tk = tid + (s5 << 8);
            int colq = tk & 15;
            int icq = (tk >> 4) & 7;
            int rl = tk >> 7;            // 0..9
            int ir = r0 - 1 + rl;
            if (ir >= 0 && ir < RES_) {
                int icb = ic0 + (icq << 2);
                float vv[16];
                #pragma unroll
                for (int i = 0; i < 4; ++i) {
                    float4 v4 = *(const float4*)(xb + (icb + i) * HW_ + ir * RES_ + (colq << 2));
                    float sc = st_s[icb + i];
                    vv[i * 4 + 0] = v4.x * sc; vv[i * 4 + 1] = v4.y * sc;
                    vv[i * 4 + 2] = v4.z * sc; vv[i * 4 + 3] = v4.w * sc;
                }
                int g = icq >> 1;
                #pragma unroll
                for (int j = 0; j < 4; ++j) {
                    int cl = 1 + (colq << 2) + j;
                    int gp = g ^ ((cl >> 2) & 3);
                    int el = (rl * XCOLS + cl) * 32 + (gp << 3) + ((icq & 1) << 2);
                    unsigned int lo = f2bf_bits(vv[0 * 4 + j]) | (f2bf_bits(vv[1 * 4 + j]) << 16);
                    unsigned int hi = f2bf_bits(vv[2 * 4 + j]) | (f2bf_bits(vv[3 * 4 + j]) << 16);
                    *(uint2*)(&Xs[el]) = make_uint2(lo, hi);
                }
            }
        }
    };

    // prologue
    for (int i = tid; i < IC_; i += 256) st_s[i] = styles[b * IC_ + i];
    {
        unsigned int* xz = (unsigned int*)Xs;
        for (int i = tid; i < XsEL / 2; i += 256) xz[i] = 0u;
    }
    __syncthreads();
    issueW(0, 0, 0);
    issueW(0, 1, 1);
    stage_x(0);

    f32x4 acc[4][8];
    #pragma unroll
    for (int mf = 0; mf < 4; ++mf)
        #pragma unroll
        for (int nf = 0; nf < 8; ++nf)
            acc[mf][nf] = (f32x4){0.f, 0.f, 0.f, 0.f};

    const int wn0 = wave << 7;
    int elA[4];
    #pragma unroll
    for (int mf = 0; mf < 4; ++mf) {
        int m = (mf << 4) + lane15;
        elA[mf] = (m << 5) + ((kg ^ ((m >> 2) & 3)) << 3);
    }
    int rB[8], cB[8];
    #pragma unroll
    for (int nf = 0; nf < 8; ++nf) {
        int n = wn0 + (nf << 4) + lane15;
        rB[nf] = n >> 6; cB[nf] = n & 63;
    }

    for (int c = 0; c < 16; ++c) {
        #pragma unroll
        for (int t = 0; t < 9; ++t) {
            if (t == 8) {
                if (c == 15) { asm volatile("s_waitcnt vmcnt(0)" ::: "memory"); }
                else         { asm volatile("s_waitcnt vmcnt(1)" ::: "memory"); }
            } else {
                asm volatile("s_waitcnt vmcnt(1)" ::: "memory");
            }
            __syncthreads();
            {   // prefetch stage s+2 (compile-time buf/t2 split; 9%3==0)
                int t2 = (t + 2 < 9) ? (t + 2) : (t - 7);
                int c2 = (t + 2 < 9) ? c : (c + 1);
                if (c2 < 16) issueW(c2, t2, (t + 2) % 3);
            }
            const int kh = t / 3, kw = t % 3;
            const unsigned short* Wbase = Wb[t % 3];
            short8 af[4];
            #pragma unroll
            for (int mf = 0; mf < 4; ++mf)
                af[mf] = *(const short8*)(Wbase + elA[mf]);
            short8 bfr[8];
            #pragma unroll
            for (int nf = 0; nf < 8; ++nf) {
                int cl = cB[nf] + kw;
                int gp = kg ^ ((cl >> 2) & 3);
                int el = ((rB[nf] + kh) * XCOLS + cl) * 32 + (gp << 3);
                bfr[nf] = *(const short8*)(Xs + el);
            }
            #pragma unroll
            for (int mf = 0; mf < 4; ++mf)
                #pragma unroll
                for (int nf = 0; nf < 8; ++nf)
                    acc[mf][nf] = __builtin_amdgcn_mfma_f32_16x16x32_bf16(
                        af[mf], bfr[nf], acc[mf][nf], 0, 0, 0);
        }
        if (c < 15) { __syncthreads(); stage_x(c + 1); }
    }

    // epilogue: demod, noise, bias, lrelu*sqrt(2)
    const float nstrength = nstr[0];
    float* outb = out + (size_t)(b * OC_ + oc0) * HW_ + nt * (NT_ROWS * RES_);
    float nz[8];
    #pragma unroll
    for (int nf = 0; nf < 8; ++nf) {
        int n = wn0 + (nf << 4) + lane15;
        nz[nf] = noise[nt * 512 + n] * nstrength;
    }
    #pragma unroll
    for (int mf = 0; mf < 4; ++mf) {
        #pragma unroll
        for (int r = 0; r < 4; ++r) {
            int ocl = (mf << 4) + (kg << 2) + r;
            float dc = dcoefs[b * OC_ + oc0 + ocl];
            float bv = bias[oc0 + ocl];
            #pragma unroll
            for (int nf = 0; nf < 8; ++nf) {
                int n = wn0 + (nf << 4) + lane15;
                float v = acc[mf][nf][r] * dc + nz[nf] + bv;
                v = (v >= 0.f ? v : 0.2f * v) * 1.4142135623730951f;
                outb[(size_t)ocl * HW_ + n] = v;
            }
        }
    }
}

// ---------------- launch ---------------------------------------------------
extern "C" void kernel_launch(void* const* d_in, const int* in_sizes, int n_in,
                              void* d_out, int out_size, void* d_ws, size_t ws_size,
                              hipStream_t stream) {
    const float* x     = (const float*)d_in[0];
    const float* w     = (const float*)d_in[1];
    const float* cw    = (const float*)d_in[2];
    const float* aw    = (const float*)d_in[3];
    const float* ab    = (const float*)d_in[4];
    const float* bias  = (const float*)d_in[5];
    const float* noise = (const float*)d_in[6];
    const float* nstr  = (const float*)d_in[7];
    float* out = (float*)d_out;

    uint8_t* ws = (uint8_t*)d_ws;
    float* styles = (float*)ws;                              // 32 KB
    float* dcoefs = (float*)(ws + 32768);                    // 32 KB
    float* S2     = (float*)(ws + 65536);                    // 1 MB
    unsigned short* wbf = (unsigned short*)(ws + 65536 + 1048576);  // 4.72 MB

    hipLaunchKernelGGL(k_styles, dim3(2048), dim3(256), 0, stream, w, aw, ab, styles);
    hipLaunchKernelGGL(k_wprep,  dim3(1024), dim3(256), 0, stream, cw, S2, wbf);
    hipLaunchKernelGGL(k_dcoef,  dim3(2048), dim3(256), 0, stream, styles, S2, dcoefs);
    hipLaunchKernelGGL(k_conv, dim3(8, 8, 16), dim3(256), 0, stream,
                       x, styles, dcoefs, wbf, bias, noise, nstr, out);
}

// Round 2
// 610.981 us; speedup vs baseline: 1.2896x; 1.2896x over previous
//
#include <hip/hip_runtime.h>
#include <hip/hip_bf16.h>
#include <cstdint>

#define B_    16
#define IC_   512
#define OC_   512
#define RES_  64
#define WDIM_ 512
#define HW_   4096

#define NT_ROWS 8
#define XROWS 10
#define XCOLS 66
#define XsEL (XROWS * XCOLS * 32)   // 21120 bf16 = 42.24 KB

typedef __attribute__((ext_vector_type(8))) short short8;
typedef __attribute__((ext_vector_type(4))) float f32x4;

__device__ __forceinline__ unsigned int f2bf_bits(float f) {
    unsigned int x = __builtin_bit_cast(unsigned int, f);
    x += 0x7fffu + ((x >> 16) & 1u);   // RNE; inputs finite
    return x >> 16;
}

// ---------------- K0: styles = w @ (aw/sqrt(512))^T + ab ----------------
__global__ __launch_bounds__(256) void k_styles(const float* __restrict__ w,
        const float* __restrict__ aw, const float* __restrict__ ab,
        float* __restrict__ styles) {
    int bx = blockIdx.x;                     // 0..2047
    int b = bx >> 7;
    int wave = threadIdx.x >> 6, lane = threadIdx.x & 63;
    int ic = ((bx & 127) << 2) + wave;
    const float* wr = w + b * WDIM_;
    const float* awr = aw + ic * WDIM_;
    float s = 0.f;
    #pragma unroll
    for (int j = 0; j < 8; ++j) {
        int k = lane + (j << 6);
        s += wr[k] * awr[k];
    }
    #pragma unroll
    for (int off = 32; off > 0; off >>= 1) s += __shfl_down(s, off);
    if (lane == 0) styles[b * IC_ + ic] = s * 0.044194173824159216f + ab[ic];
}

// ---------------- K1: S2[oc,ic] = sum_k cw^2 ; wbf = bf16 pack ------------
// wbf layout: [t(9)][chunk(16)][oc(512)][ic32]   (plain, 4.72 MB)
__global__ __launch_bounds__(256) void k_wprep(const float* __restrict__ cw,
        float* __restrict__ S2, unsigned short* __restrict__ wbf) {
    int gid = blockIdx.x * 256 + threadIdx.x;   // 0..262143
    int oc = gid >> 9, ic = gid & 511;
    const float* p = cw + gid * 9;
    float v[9]; float ss = 0.f;
    #pragma unroll
    for (int t = 0; t < 9; ++t) { v[t] = p[t]; ss += v[t] * v[t]; }
    S2[gid] = ss;
    int chunk = ic >> 5;
    int base = (chunk * 512 + oc) * 32 + (ic & 31);
    #pragma unroll
    for (int t = 0; t < 9; ++t)
        wbf[t * (16 * 512 * 32) + base] = (unsigned short)f2bf_bits(v[t]);
}

// ---------------- K2: dcoefs[b,oc] = rsqrt(sum_ic styles^2 * S2 + 1e-8) -----
__global__ __launch_bounds__(256) void k_dcoef(const float* __restrict__ styles,
        const float* __restrict__ S2, float* __restrict__ dcoefs) {
    int bx = blockIdx.x;
    int b = bx >> 7;
    int wave = threadIdx.x >> 6, lane = threadIdx.x & 63;
    int oc = ((bx & 127) << 2) + wave;
    const float* st = styles + b * IC_;
    const float* s2 = S2 + oc * IC_;
    float s = 0.f;
    #pragma unroll
    for (int j = 0; j < 8; ++j) {
        int k = lane + (j << 6);
        float a = st[k];
        s += a * a * s2[k];
    }
    #pragma unroll
    for (int off = 32; off > 0; off >>= 1) s += __shfl_down(s, off);
    if (lane == 0) dcoefs[b * OC_ + oc] = rsqrtf(s + 1e-8f);
}

// ---------------- K3: main conv -------------------------------------------
// grid (8 nt, 8 oct, 16 b), 256 thr (4 waves). BM=64 oc, BN=512 (8 rows).
// A (weights) read global->reg (L1-cached); only X lives in LDS.
__global__ __launch_bounds__(256, 2) void k_conv(
        const float* __restrict__ x, const float* __restrict__ styles,
        const float* __restrict__ dcoefs, const unsigned short* __restrict__ wbf,
        const float* __restrict__ bias, const float* __restrict__ noise,
        const float* __restrict__ nstr, float* __restrict__ out) {

    __shared__ __align__(16) unsigned short Xs[XsEL];        // 42.24 KB
    __shared__ float st_s[IC_];                              // 2 KB

    const int tid = threadIdx.x;
    const int lane = tid & 63, wave = tid >> 6;
    const int lane15 = lane & 15, kg = lane >> 4;
    const int nt = blockIdx.x, oct = blockIdx.y, b = blockIdx.z;
    const int oc0 = oct * 64, r0 = nt * NT_ROWS;
    const float* xb = x + (size_t)b * IC_ * HW_;

    // A-frag global base: frag mf at +mf*512 elements; per-lane fixed offset.
    const unsigned short* wlane = wbf + (size_t)(oc0 + lane15) * 32 + (kg << 3);

    auto loadA = [&](int c2, int t2, short8* dst) {
        const unsigned short* g = wlane + (size_t)(t2 * 16 + c2) * (512 * 32);
        #pragma unroll
        for (int mf = 0; mf < 4; ++mf)
            dst[mf] = *(const short8*)(g + (mf << 9));
    };

    // stage: strided cols {q,q+16,q+32,q+48} so write bank-slot varies per instr
    auto stage_x = [&](int c) {
        const int ic0 = c << 5;
        #pragma unroll
        for (int s5 = 0; s5 < 5; ++s5) {
            int tk = tid + (s5 << 8);
            int q   = tk & 15;
            int icq = (tk >> 4) & 7;
            int rl  = tk >> 7;            // 0..9
            int ir = r0 - 1 + rl;
            if (ir >= 0 && ir < RES_) {
                int icb = ic0 + (icq << 2);
                const int g = icq >> 1;
                float sc[4];
                #pragma unroll
                for (int i = 0; i < 4; ++i) sc[i] = st_s[icb + i];
                const float* xr = xb + (size_t)ir * RES_ + q;
                float v[4][4];
                #pragma unroll
                for (int i = 0; i < 4; ++i)
                    #pragma unroll
                    for (int j = 0; j < 4; ++j)
                        v[i][j] = xr[(size_t)(icb + i) * HW_ + (j << 4)] * sc[i];
                #pragma unroll
                for (int j = 0; j < 4; ++j) {
                    int cl = 1 + q + (j << 4);
                    int gp = g ^ ((cl >> 1) & 3);
                    int el = (rl * XCOLS + cl) * 32 + (gp << 3) + ((icq & 1) << 2);
                    unsigned int lo = f2bf_bits(v[0][j]) | (f2bf_bits(v[1][j]) << 16);
                    unsigned int hi = f2bf_bits(v[2][j]) | (f2bf_bits(v[3][j]) << 16);
                    *(uint2*)(&Xs[el]) = make_uint2(lo, hi);
                }
            }
        }
    };

    // prologue
    for (int i = tid; i < IC_; i += 256) st_s[i] = styles[b * IC_ + i];
    {
        unsigned int* xz = (unsigned int*)Xs;
        for (int i = tid; i < XsEL / 2; i += 256) xz[i] = 0u;
    }
    __syncthreads();
    stage_x(0);

    f32x4 acc[4][8];
    #pragma unroll
    for (int mf = 0; mf < 4; ++mf)
        #pragma unroll
        for (int nf = 0; nf < 8; ++nf)
            acc[mf][nf] = (f32x4){0.f, 0.f, 0.f, 0.f};

    const int wn0 = wave << 7;
    // B-frag address precompute (all-constant indices after unroll)
    int rb2112[8];        // rB*66*32
    int colel[3][8];      // (cB+kw)*32 + slot(kg,cl)*8
    #pragma unroll
    for (int nf = 0; nf < 8; ++nf) {
        int n = wn0 + (nf << 4) + lane15;
        rb2112[nf] = (n >> 6) * (XCOLS * 32);
        int cB = n & 63;
        #pragma unroll
        for (int kw = 0; kw < 3; ++kw) {
            int cl = cB + kw;
            int gp = kg ^ ((cl >> 1) & 3);
            colel[kw][nf] = cl * 32 + (gp << 3);
        }
    }

    short8 afc[4];
    loadA(0, 0, afc);
    __syncthreads();

    for (int c = 0; c < 16; ++c) {
        #pragma unroll
        for (int t = 0; t < 9; ++t) {
            // prefetch next A (wraps harmlessly at the very end)
            short8 afn[4];
            {
                int c2 = (t < 8) ? c : ((c + 1) & 15);
                int t2 = (t < 8) ? (t + 1) : 0;
                loadA(c2, t2, afn);
            }
            const int kh = t / 3, kw = t % 3;
            short8 bfr[8];
            #pragma unroll
            for (int nf = 0; nf < 8; ++nf) {
                int el = rb2112[nf] + kh * (XCOLS * 32) + colel[kw][nf];
                bfr[nf] = *(const short8*)(Xs + el);
            }
            #pragma unroll
            for (int mf = 0; mf < 4; ++mf)
                #pragma unroll
                for (int nf = 0; nf < 8; ++nf)
                    acc[mf][nf] = __builtin_amdgcn_mfma_f32_16x16x32_bf16(
                        afc[mf], bfr[nf], acc[mf][nf], 0, 0, 0);
            #pragma unroll
            for (int mf = 0; mf < 4; ++mf) afc[mf] = afn[mf];
        }
        if (c < 15) { __syncthreads(); stage_x(c + 1); __syncthreads(); }
    }

    // epilogue: demod, noise, bias, lrelu*sqrt(2)
    const float nstrength = nstr[0];
    float* outb = out + (size_t)(b * OC_ + oc0) * HW_ + nt * (NT_ROWS * RES_);
    float nz[8];
    #pragma unroll
    for (int nf = 0; nf < 8; ++nf) {
        int n = wn0 + (nf << 4) + lane15;
        nz[nf] = noise[nt * 512 + n] * nstrength;
    }
    #pragma unroll
    for (int mf = 0; mf < 4; ++mf) {
        #pragma unroll
        for (int r = 0; r < 4; ++r) {
            int ocl = (mf << 4) + (kg << 2) + r;
            float dc = dcoefs[b * OC_ + oc0 + ocl];
            float bv = bias[oc0 + ocl];
            #pragma unroll
            for (int nf = 0; nf < 8; ++nf) {
                int n = wn0 + (nf << 4) + lane15;
                float v = acc[mf][nf][r] * dc + nz[nf] + bv;
                v = (v >= 0.f ? v : 0.2f * v) * 1.4142135623730951f;
                outb[(size_t)ocl * HW_ + n] = v;
            }
        }
    }
}

// ---------------- launch ---------------------------------------------------
extern "C" void kernel_launch(void* const* d_in, const int* in_sizes, int n_in,
                              void* d_out, int out_size, void* d_ws, size_t ws_size,
                              hipStream_t stream) {
    const float* x     = (const float*)d_in[0];
    const float* w     = (const float*)d_in[1];
    const float* cw    = (const float*)d_in[2];
    const float* aw    = (const float*)d_in[3];
    const float* ab    = (const float*)d_in[4];
    const float* bias  = (const float*)d_in[5];
    const float* noise = (const float*)d_in[6];
    const float* nstr  = (const float*)d_in[7];
    float* out = (float*)d_out;

    uint8_t* ws = (uint8_t*)d_ws;
    float* styles = (float*)ws;                              // 32 KB
    float* dcoefs = (float*)(ws + 32768);                    // 32 KB
    float* S2     = (float*)(ws + 65536);                    // 1 MB
    unsigned short* wbf = (unsigned short*)(ws + 65536 + 1048576);  // 4.72 MB

    hipLaunchKernelGGL(k_styles, dim3(2048), dim3(256), 0, stream, w, aw, ab, styles);
    hipLaunchKernelGGL(k_wprep,  dim3(1024), dim3(256), 0, stream, cw, S2, wbf);
    hipLaunchKernelGGL(k_dcoef,  dim3(2048), dim3(256), 0, stream, styles, S2, dcoefs);
    hipLaunchKernelGGL(k_conv, dim3(8, 8, 16), dim3(256), 0, stream,
                       x, styles, dcoefs, wbf, bias, noise, nstr, out);
}